// Round 4
// baseline (112.192 us; speedup 1.0000x reference)
//
#include <hip/hip_runtime.h>
#include <cmath>

// Problem constants (fixed by the reference's init kwargs):
//   POS_FREQS=31, W_MIN=0.1, W_MAX=1.0, PATCH=16 -> grid H=64 (row 63 padded), W=32
//   batch_triangles: [64,128,3,2] f32, lengths: [64] i32
//   outputs: mag [64,1,64,32] f32 then phase [64,1,64,32] f32, concatenated flat.
//
// R4 = MEASUREMENT ROUND: kernel body identical to R3 (passed, 73.91 us).
// kernel_launch launches it 3x back-to-back (idempotent writes to d_out) so
// dur_us = overhead + 3*t_kernel, exposing the kernel's true duration, which
// has never been directly observed (it is hidden below the ~40 us poison
// fills in the top-5 counter listing).
#define BB     64
#define MAXN   128
#define HH     64
#define WW     32
#define NFREQ  (HH*WW)      // 2048
#define BLK    256
#define NWAVE  4            // waves per block; each wave covers 64 points
#define PGRPS  (NFREQ/64)   // 32 point-groups of 64 points per batch elem

// pos_w[k] = float32(0.1 * (10^(1/30))^k) — bit-exactness validated previously.
__device__ __constant__ float c_posw[31] = {
    0.10000000000f, 0.10797751623f, 0.11659144012f, 0.12589254118f,
    0.13593563909f, 0.14677992676f, 0.15848931925f, 0.17113283042f,
    0.18478497970f, 0.19952623150f, 0.21544346900f, 0.23263050672f,
    0.25118864315f, 0.27122725793f, 0.29286445646f, 0.31622776602f,
    0.34145488738f, 0.36869450645f, 0.39810717055f, 0.42986623483f,
    0.46415888336f, 0.50118723363f, 0.54116952655f, 0.58434141336f,
    0.63095734448f, 0.68129206906f, 0.73564225446f, 0.79432823472f,
    0.85769589859f, 0.92611872813f, 1.00000000000f
};

// float32 constants exactly as the reference builds them:
#define PI_F      3.14159274101257324f   // np.float32(np.pi)
#define TWOPI_F   6.28318548202514648f   // 2*pi_f
#define FOURPI2_F ((4.0f * PI_F) * PI_F) // np.float32(4)*pi*pi

// sin(2*pi*x), cos(2*pi*x) via hardware v_sin_f32/v_cos_f32 (input in
// REVOLUTIONS, reduced to [0,1) with v_fract_f32 first).
__device__ __forceinline__ void sincos_2pi(float x, float* s, float* c) {
    float r = __builtin_amdgcn_fractf(x);
    *s = __builtin_amdgcn_sinf(r);
    *c = __builtin_amdgcn_cosf(r);
}

// Hot-loop mask quantities only (exact mul/mul/add, no FMA contraction).
struct Mask {
    float U_, V_, S;
    bool  sp;       // special AND not the DC lane (DC handled analytically)
};

__device__ __forceinline__ Mask pre_mask(float U, float V, float4 A4, float4 B4, bool dc) {
    Mask e;
    e.U_ = __fadd_rn(__fmul_rn(U, A4.z), __fmul_rn(V, A4.w));
    e.V_ = __fadd_rn(__fmul_rn(U, B4.x), __fmul_rn(V, B4.y));
    e.S  = __fadd_rn(e.U_, e.V_);
    e.sp = ((e.U_ == 0.0f) || (e.V_ == 0.0f) || (e.S == 0.0f)) && !dc;
    return e;
}

// FAST path: pure normal-case algebra; k = (2*area/4pi^2) * rcp(U_ V_ S).
__device__ __forceinline__ void eval_fast(const Mask& e, float U, float V,
                                          float4 A4, float4 B4,
                                          float& accR, float& accI) {
    const float tq = U * A4.x + V * A4.y;
    const float tr = tq + e.U_;
    const float ts = tr + e.V_;
    float sq, cq, sr, cr, ss, cs;
    sincos_2pi(tq, &sq, &cq);
    sincos_2pi(tr, &sr, &cr);
    sincos_2pi(ts, &ss, &cs);
    const float p1 = __builtin_amdgcn_rcpf((e.U_ * e.V_) * e.S);
    const float k  = B4.w * p1;
    const float re = e.S * cr - e.U_ * cs - e.V_ * cq;
    const float im = e.U_ * ss - e.S * sr + e.V_ * sq;
    accR = fmaf(k, re, accR);
    accI = fmaf(k, im, accI);
}

// COLD path: full branchless 4-way coefficient code, recomputed from LDS.
__device__ __forceinline__ void eval_slow_n(float U, float V, float4 A4, float4 B4,
                                            float& accR, float& accI) {
    const float U_ = __fadd_rn(__fmul_rn(U, A4.z), __fmul_rn(V, A4.w));
    const float V_ = __fadd_rn(__fmul_rn(U, B4.x), __fmul_rn(V, B4.y));
    const float S  = __fadd_rn(U_, V_);
    const bool uz = (U_ == 0.0f), vz = (V_ == 0.0f), sz = (S == 0.0f);

    const float tq = U * A4.x + V * A4.y;
    const float tr = tq + U_;
    const float ts = tr + V_;
    float sq, cq, sr, cr, ss, cs;
    sincos_2pi(tq, &sq, &cq);
    sincos_2pi(tr, &sr, &cr);
    sincos_2pi(ts, &ss, &cs);

    const float area = 0.5f * B4.z;
    const bool zero = uz && vz;
    const bool diag = sz && !zero;
    const bool u_m  = uz && !zero;
    const bool v_m  = vz && !zero;
    const bool nrm  = !(uz || vz || sz);

    const float twU = TWOPI_F * U_;
    const float twV = TWOPI_F * V_;

    const float Ac = nrm ? -U_ : (u_m ? 1.0f : 0.0f);
    const float Bc = nrm ?  S  : ((diag || v_m) ? 1.0f : 0.0f);
    const float Cc = nrm ? -V_ : -1.0f;
    const float Dc = v_m  ? twU : 0.0f;
    const float Ec = diag ? twU : (u_m ? twV : 0.0f);

    const float d1  = u_m ? V_ : U_;
    const float den = nrm ? (U_ * V_) * S : d1 * d1;
    const float p1  = __builtin_amdgcn_rcpf(FOURPI2_F * den);
    const float sgn = (diag || u_m) ? -2.0f : 2.0f;
    const float k   = zero ? 0.0f : sgn * area * p1;

    const float re =  Ac * cs + Bc * cr + Cc * cq + Dc * sr + Ec * sq;
    const float im = -(Ac * ss + Bc * sr + Cc * sq) + Dc * cr + Ec * cq;

    accR = fmaf(k, re, accR) + (zero ? area : 0.0f);
    accI = fmaf(k, im, accI);
}

__global__ __launch_bounds__(BLK) void poly_cft_fused(
    const float* __restrict__ tris,    // [64,128,3,2]
    const int*   __restrict__ lengths, // [64]
    float*       __restrict__ out)     // [2*64*2048]
{
    __shared__ float4 sA[MAXN];           // xq, yq, e1x, e1y          (2 KB)
    __shared__ float4 sB[MAXN];           // e2x, e2y, 2a, 2a/4pi^2    (2 KB)
    __shared__ float2 s_red[NWAVE][64];   // reduction scratch         (2 KB)

    const int pg   = blockIdx.x;           // 0..31 point group
    const int b    = blockIdx.y;           // 0..63 batch elem
    const int lane = threadIdx.x & 63;
    const int wv   = threadIdx.x >> 6;     // 0..3 wave id
    const int p    = (pg << 6) | lane;     // 0..2047 freq point
    const int h    = p >> 5;
    const int w    = p & 31;
    const bool dc  = (p == 992);           // h==31 && w==0 : U=V=0 lane

    const int N = lengths[b];

    // Stage all 128 triangles of this b once per block.
    if (threadIdx.x < MAXN) {
        const float2* tp = (const float2*)(tris + ((size_t)b * MAXN + threadIdx.x) * 6);
        const float2 v0 = tp[0], v1 = tp[1], v2 = tp[2];
        const float xq = v0.x, yq = v0.y, xr = v1.x, yr = v1.y, xs = v2.x, ys = v2.y;
        const float det  = xq * (yr - ys) + xr * (ys - yq) + xs * (yq - yr);
        const float area = fabsf(0.5f * det);
        const float a2   = 2.0f * area;
        sA[threadIdx.x] = make_float4(xq, yq, xr - xq, yr - yq);
        sB[threadIdx.x] = make_float4(xs - xr, ys - yr, a2, a2 * (1.0f / FOURPI2_F));
    }
    __syncthreads();

    // U = Wx[h], V = Wy[w] from the validated constant table.
    float U;
    if (h < 31)       U = -c_posw[30 - h];
    else if (h == 31) U = 0.0f;
    else if (h < 63)  U = c_posw[h - 32];
    else              U = 0.0f;   // padded row (masked before output)
    const float V = (w == 0) ? 0.0f : c_posw[w - 1];

    float accR = 0.0f, accI = 0.0f;

    // Quad loop: wave wv evaluates (n, n+4, n+8, n+12); per-wave accumulation
    // order (wv, wv+4, wv+8, ...) is preserved exactly in both branches.
    int n = wv;
    for (; n + 3 * NWAVE < N; n += 4 * NWAVE) {
        const float4 a0 = sA[n],             b0 = sB[n];
        const float4 a1 = sA[n +     NWAVE], b1 = sB[n +     NWAVE];
        const float4 a2 = sA[n + 2 * NWAVE], b2 = sB[n + 2 * NWAVE];
        const float4 a3 = sA[n + 3 * NWAVE], b3 = sB[n + 3 * NWAVE];
        const Mask ea = pre_mask(U, V, a0, b0, dc);
        const Mask eb = pre_mask(U, V, a1, b1, dc);
        const Mask ec = pre_mask(U, V, a2, b2, dc);
        const Mask ed = pre_mask(U, V, a3, b3, dc);

        if (__builtin_expect((long)__ballot(ea.sp || eb.sp || ec.sp || ed.sp), 0)) {
            eval_slow_n(U, V, a0, b0, accR, accI);
            eval_slow_n(U, V, a1, b1, accR, accI);
            eval_slow_n(U, V, a2, b2, accR, accI);
            eval_slow_n(U, V, a3, b3, accR, accI);
        } else {
            eval_fast(ea, U, V, a0, b0, accR, accI);
            eval_fast(eb, U, V, a1, b1, accR, accI);
            eval_fast(ec, U, V, a2, b2, accR, accI);
            eval_fast(ed, U, V, a3, b3, accR, accI);
        }
    }

    // Pair remainder.
    for (; n + NWAVE < N; n += 2 * NWAVE) {
        const float4 a0 = sA[n],         b0 = sB[n];
        const float4 a1 = sA[n + NWAVE], b1 = sB[n + NWAVE];
        const Mask ea = pre_mask(U, V, a0, b0, dc);
        const Mask eb = pre_mask(U, V, a1, b1, dc);
        if (__builtin_expect((long)__ballot(ea.sp || eb.sp), 0)) {
            eval_slow_n(U, V, a0, b0, accR, accI);
            eval_slow_n(U, V, a1, b1, accR, accI);
        } else {
            eval_fast(ea, U, V, a0, b0, accR, accI);
            eval_fast(eb, U, V, a1, b1, accR, accI);
        }
    }

    // Single remainder (at most one triangle per wave).
    for (; n < N; n += NWAVE) {
        const float4 a0 = sA[n], b0 = sB[n];
        const Mask ea = pre_mask(U, V, a0, b0, dc);
        if (__builtin_expect((long)__ballot(ea.sp), 0)) {
            eval_slow_n(U, V, a0, b0, accR, accI);
        } else {
            eval_fast(ea, U, V, a0, b0, accR, accI);
        }
    }

    s_red[wv][lane] = make_float2(accR, accI);
    __syncthreads();

    if (wv == 0) {
        float R = 0.0f, I = 0.0f;
#pragma unroll
        for (int k = 0; k < NWAVE; ++k) {
            const float2 v = s_red[k][lane];
            R += v.x;
            I += v.y;
        }
        // numpy's masked segment-sum adds exact +0.0 for invalid slots,
        // flipping -0.0 -> +0.0; reproduce (affects only zero signs).
        R += 0.0f;
        I += 0.0f;

        // DC lane (p==992): FT = sum of areas (exact analytic value).
        if (pg == 15) {
            float a0 = (lane < N)      ? 0.5f * sB[lane].z      : 0.0f;
            float a1 = (lane + 64 < N) ? 0.5f * sB[lane + 64].z : 0.0f;
            float s = a0 + a1;
#pragma unroll
            for (int o = 32; o > 0; o >>= 1) s += __shfl_down(s, o, 64);
            s = __shfl(s, 0, 64);
            if (lane == 32) { R = s; I = 0.0f; }
        }

        if (h == 63) { R = 0.0f; I = 0.0f; }   // pad row

        const float m2 = __fadd_rn(__fmul_rn(R, R), __fmul_rn(I, I));
        float mag, ph;
        if (m2 == 0.0f) {
            mag = 0.0f;
            ph  = atan2f(I, 1.0f);   // angle(0) = 0 semantics
        } else {
            mag = log1pf(sqrtf(m2));
            ph  = atan2f(I, R);
        }

        const int o = b * NFREQ + p;
        out[o]              = mag;   // mag block [64,1,64,32]
        out[BB * NFREQ + o] = ph;    // phase block follows
    }
}

extern "C" void kernel_launch(void* const* d_in, const int* in_sizes, int n_in,
                              void* d_out, int out_size, void* d_ws, size_t ws_size,
                              hipStream_t stream) {
    const float* tris    = (const float*)d_in[0]; // [64,128,3,2] f32
    const int*   lengths = (const int*)d_in[1];   // [64] i32
    float*       out     = (float*)d_out;         // [2*64*2048] f32

    // DIAGNOSTIC: 3 identical, idempotent launches. dur_us = ovh + 3*t_kernel.
    poly_cft_fused<<<dim3(PGRPS, BB), dim3(BLK), 0, stream>>>(tris, lengths, out);
    poly_cft_fused<<<dim3(PGRPS, BB), dim3(BLK), 0, stream>>>(tris, lengths, out);
    poly_cft_fused<<<dim3(PGRPS, BB), dim3(BLK), 0, stream>>>(tris, lengths, out);
}

// Round 5
// 75.892 us; speedup vs baseline: 1.4783x; 1.4783x over previous
//
#include <hip/hip_runtime.h>
#include <cmath>

// Problem constants (fixed by the reference's init kwargs):
//   POS_FREQS=31, W_MIN=0.1, W_MAX=1.0, PATCH=16 -> grid H=64 (row 63 padded), W=32
//   batch_triangles: [64,128,3,2] f32, lengths: [64] i32
//   outputs: mag [64,1,64,32] f32 then phase [64,1,64,32] f32, concatenated flat.
//
// R5: occupancy round. R4 measured t_kernel ~= 19us vs a ~4us pipe floor ->
// stall-bound. R3's liveness cut was undone by cross-branch CSE (both paths
// computed identical speculatable sincos -> hoisted above the ballot, VGPR
// stayed high, 2-3 waves/SIMD). This round:
//   - pre_mask_ext consumes A4/B4 immediately; only {U_,V_,S,tq,zk,sp} live
//     across the ballot (5 floats/eval instead of ~19).
//   - slow path re-reads LDS and recomputes from asm-LAUNDERED U,V so no
//     expression is textually shared with the fast path -> no hoisting.
//   - trig only inside the fast branch; no launch_bounds min-wave forcing.
#define BB     64
#define MAXN   128
#define HH     64
#define WW     32
#define NFREQ  (HH*WW)      // 2048
#define BLK    256
#define NWAVE  4            // waves per block; each wave covers 64 points
#define PGRPS  (NFREQ/64)   // 32 point-groups of 64 points per batch elem

// pos_w[k] = float32(0.1 * (10^(1/30))^k) — bit-exactness validated previously.
__device__ __constant__ float c_posw[31] = {
    0.10000000000f, 0.10797751623f, 0.11659144012f, 0.12589254118f,
    0.13593563909f, 0.14677992676f, 0.15848931925f, 0.17113283042f,
    0.18478497970f, 0.19952623150f, 0.21544346900f, 0.23263050672f,
    0.25118864315f, 0.27122725793f, 0.29286445646f, 0.31622776602f,
    0.34145488738f, 0.36869450645f, 0.39810717055f, 0.42986623483f,
    0.46415888336f, 0.50118723363f, 0.54116952655f, 0.58434141336f,
    0.63095734448f, 0.68129206906f, 0.73564225446f, 0.79432823472f,
    0.85769589859f, 0.92611872813f, 1.00000000000f
};

// float32 constants exactly as the reference builds them:
#define PI_F      3.14159274101257324f   // np.float32(np.pi)
#define TWOPI_F   6.28318548202514648f   // 2*pi_f
#define FOURPI2_F ((4.0f * PI_F) * PI_F) // np.float32(4)*pi*pi

// sin(2*pi*x), cos(2*pi*x) via hardware v_sin_f32/v_cos_f32 (input in
// REVOLUTIONS, reduced to [0,1) with v_fract_f32 first).
__device__ __forceinline__ void sincos_2pi(float x, float* s, float* c) {
    float r = __builtin_amdgcn_fractf(x);
    *s = __builtin_amdgcn_sinf(r);
    *c = __builtin_amdgcn_cosf(r);
}

// Value-identical, optimizer-opaque: prevents cross-branch CSE/hoisting.
__device__ __forceinline__ float launder(float x) {
    asm volatile("" : "+v"(x));
    return x;
}

// Hot-loop precompute: consumes A4/B4 immediately so they die before the
// branch. Live across the ballot: U_, V_, S, tq, zk, sp only.
struct PreX {
    float U_, V_, S, tq, zk;
    bool  sp;       // special AND not the DC lane (DC handled analytically)
};

__device__ __forceinline__ PreX pre_mask_ext(float U, float V, float4 A4, float4 B4, bool dc) {
    PreX e;
    e.U_ = __fadd_rn(__fmul_rn(U, A4.z), __fmul_rn(V, A4.w));
    e.V_ = __fadd_rn(__fmul_rn(U, B4.x), __fmul_rn(V, B4.y));
    e.S  = __fadd_rn(e.U_, e.V_);
    e.sp = ((e.U_ == 0.0f) || (e.V_ == 0.0f) || (e.S == 0.0f)) && !dc;
    e.tq = U * A4.x + V * A4.y;
    e.zk = B4.w;
    return e;
}

// FAST path: trig computed HERE (inside the branch), transient liveness only.
__device__ __forceinline__ void eval_fast_x(const PreX& e, float& accR, float& accI) {
    const float tr = e.tq + e.U_;
    const float ts = tr + e.V_;
    float sq, cq, sr, cr, ss, cs;
    sincos_2pi(e.tq, &sq, &cq);
    sincos_2pi(tr, &sr, &cr);
    sincos_2pi(ts, &ss, &cs);
    const float p1 = __builtin_amdgcn_rcpf((e.U_ * e.V_) * e.S);
    const float k  = e.zk * p1;
    const float re = e.S * cr - e.U_ * cs - e.V_ * cq;
    const float im = e.U_ * ss - e.S * sr + e.V_ * sq;
    accR = fmaf(k, re, accR);
    accI = fmaf(k, im, accI);
}

// COLD path: re-reads LDS, recomputes everything from LAUNDERED U,V so the
// optimizer cannot unify any of this with the fast path (values identical).
// Full branchless 4-way coefficient code, valid for ALL cases.
__device__ __forceinline__ void eval_slow_lds(const float4* sA, const float4* sB, int n,
                                              float U0, float V0, float& accR, float& accI) {
    const float4 A4 = sA[n];
    const float4 B4 = sB[n];
    const float U = launder(U0);
    const float V = launder(V0);

    const float U_ = __fadd_rn(__fmul_rn(U, A4.z), __fmul_rn(V, A4.w));
    const float V_ = __fadd_rn(__fmul_rn(U, B4.x), __fmul_rn(V, B4.y));
    const float S  = __fadd_rn(U_, V_);
    const bool uz = (U_ == 0.0f), vz = (V_ == 0.0f), sz = (S == 0.0f);

    const float tq = U * A4.x + V * A4.y;
    const float tr = tq + U_;
    const float ts = tr + V_;
    float sq, cq, sr, cr, ss, cs;
    sincos_2pi(tq, &sq, &cq);
    sincos_2pi(tr, &sr, &cr);
    sincos_2pi(ts, &ss, &cs);

    const float area = 0.5f * B4.z;
    const bool zero = uz && vz;
    const bool diag = sz && !zero;
    const bool u_m  = uz && !zero;
    const bool v_m  = vz && !zero;
    const bool nrm  = !(uz || vz || sz);

    const float twU = TWOPI_F * U_;
    const float twV = TWOPI_F * V_;

    const float Ac = nrm ? -U_ : (u_m ? 1.0f : 0.0f);
    const float Bc = nrm ?  S  : ((diag || v_m) ? 1.0f : 0.0f);
    const float Cc = nrm ? -V_ : -1.0f;
    const float Dc = v_m  ? twU : 0.0f;
    const float Ec = diag ? twU : (u_m ? twV : 0.0f);

    const float d1  = u_m ? V_ : U_;
    const float den = nrm ? (U_ * V_) * S : d1 * d1;
    const float p1  = __builtin_amdgcn_rcpf(FOURPI2_F * den);
    const float sgn = (diag || u_m) ? -2.0f : 2.0f;
    const float k   = zero ? 0.0f : sgn * area * p1;

    const float re =  Ac * cs + Bc * cr + Cc * cq + Dc * sr + Ec * sq;
    const float im = -(Ac * ss + Bc * sr + Cc * sq) + Dc * cr + Ec * cq;

    accR = fmaf(k, re, accR) + (zero ? area : 0.0f);
    accI = fmaf(k, im, accI);
}

__global__ __launch_bounds__(BLK) void poly_cft_fused(
    const float* __restrict__ tris,    // [64,128,3,2]
    const int*   __restrict__ lengths, // [64]
    float*       __restrict__ out)     // [2*64*2048]
{
    __shared__ float4 sA[MAXN];           // xq, yq, e1x, e1y          (2 KB)
    __shared__ float4 sB[MAXN];           // e2x, e2y, 2a, 2a/4pi^2    (2 KB)
    __shared__ float2 s_red[NWAVE][64];   // reduction scratch         (2 KB)

    const int pg   = blockIdx.x;           // 0..31 point group
    const int b    = blockIdx.y;           // 0..63 batch elem
    const int lane = threadIdx.x & 63;
    const int wv   = threadIdx.x >> 6;     // 0..3 wave id
    const int p    = (pg << 6) | lane;     // 0..2047 freq point
    const int h    = p >> 5;
    const int w    = p & 31;
    const bool dc  = (p == 992);           // h==31 && w==0 : U=V=0 lane

    const int N = lengths[b];

    // Stage all 128 triangles of this b once per block.
    if (threadIdx.x < MAXN) {
        const float2* tp = (const float2*)(tris + ((size_t)b * MAXN + threadIdx.x) * 6);
        const float2 v0 = tp[0], v1 = tp[1], v2 = tp[2];
        const float xq = v0.x, yq = v0.y, xr = v1.x, yr = v1.y, xs = v2.x, ys = v2.y;
        const float det  = xq * (yr - ys) + xr * (ys - yq) + xs * (yq - yr);
        const float area = fabsf(0.5f * det);
        const float a2   = 2.0f * area;
        sA[threadIdx.x] = make_float4(xq, yq, xr - xq, yr - yq);
        sB[threadIdx.x] = make_float4(xs - xr, ys - yr, a2, a2 * (1.0f / FOURPI2_F));
    }
    __syncthreads();

    // U = Wx[h], V = Wy[w] from the validated constant table.
    float U;
    if (h < 31)       U = -c_posw[30 - h];
    else if (h == 31) U = 0.0f;
    else if (h < 63)  U = c_posw[h - 32];
    else              U = 0.0f;   // padded row (masked before output)
    const float V = (w == 0) ? 0.0f : c_posw[w - 1];

    float accR = 0.0f, accI = 0.0f;

    // Quad loop: wave wv evaluates (n, n+4, n+8, n+12); per-wave accumulation
    // order (wv, wv+4, wv+8, ...) is preserved exactly in both branches.
    int n = wv;
    for (; n + 3 * NWAVE < N; n += 4 * NWAVE) {
        const PreX ea = pre_mask_ext(U, V, sA[n],             sB[n],             dc);
        const PreX eb = pre_mask_ext(U, V, sA[n +     NWAVE], sB[n +     NWAVE], dc);
        const PreX ec = pre_mask_ext(U, V, sA[n + 2 * NWAVE], sB[n + 2 * NWAVE], dc);
        const PreX ed = pre_mask_ext(U, V, sA[n + 3 * NWAVE], sB[n + 3 * NWAVE], dc);

        if (__builtin_expect((long)__ballot(ea.sp || eb.sp || ec.sp || ed.sp), 0)) {
            eval_slow_lds(sA, sB, n,             U, V, accR, accI);
            eval_slow_lds(sA, sB, n +     NWAVE, U, V, accR, accI);
            eval_slow_lds(sA, sB, n + 2 * NWAVE, U, V, accR, accI);
            eval_slow_lds(sA, sB, n + 3 * NWAVE, U, V, accR, accI);
        } else {
            eval_fast_x(ea, accR, accI);
            eval_fast_x(eb, accR, accI);
            eval_fast_x(ec, accR, accI);
            eval_fast_x(ed, accR, accI);
        }
    }

    // Pair remainder.
    for (; n + NWAVE < N; n += 2 * NWAVE) {
        const PreX ea = pre_mask_ext(U, V, sA[n],         sB[n],         dc);
        const PreX eb = pre_mask_ext(U, V, sA[n + NWAVE], sB[n + NWAVE], dc);
        if (__builtin_expect((long)__ballot(ea.sp || eb.sp), 0)) {
            eval_slow_lds(sA, sB, n,         U, V, accR, accI);
            eval_slow_lds(sA, sB, n + NWAVE, U, V, accR, accI);
        } else {
            eval_fast_x(ea, accR, accI);
            eval_fast_x(eb, accR, accI);
        }
    }

    // Single remainder (at most one triangle per wave).
    for (; n < N; n += NWAVE) {
        const PreX ea = pre_mask_ext(U, V, sA[n], sB[n], dc);
        if (__builtin_expect((long)__ballot(ea.sp), 0)) {
            eval_slow_lds(sA, sB, n, U, V, accR, accI);
        } else {
            eval_fast_x(ea, accR, accI);
        }
    }

    s_red[wv][lane] = make_float2(accR, accI);
    __syncthreads();

    if (wv == 0) {
        float R = 0.0f, I = 0.0f;
#pragma unroll
        for (int k = 0; k < NWAVE; ++k) {
            const float2 v = s_red[k][lane];
            R += v.x;
            I += v.y;
        }
        // numpy's masked segment-sum adds exact +0.0 for invalid slots,
        // flipping -0.0 -> +0.0; reproduce (affects only zero signs).
        R += 0.0f;
        I += 0.0f;

        // DC lane (p==992): FT = sum of areas (exact analytic value).
        if (pg == 15) {
            float a0 = (lane < N)      ? 0.5f * sB[lane].z      : 0.0f;
            float a1 = (lane + 64 < N) ? 0.5f * sB[lane + 64].z : 0.0f;
            float s = a0 + a1;
#pragma unroll
            for (int o = 32; o > 0; o >>= 1) s += __shfl_down(s, o, 64);
            s = __shfl(s, 0, 64);
            if (lane == 32) { R = s; I = 0.0f; }
        }

        if (h == 63) { R = 0.0f; I = 0.0f; }   // pad row

        const float m2 = __fadd_rn(__fmul_rn(R, R), __fmul_rn(I, I));
        float mag, ph;
        if (m2 == 0.0f) {
            mag = 0.0f;
            ph  = atan2f(I, 1.0f);   // angle(0) = 0 semantics
        } else {
            mag = log1pf(sqrtf(m2));
            ph  = atan2f(I, R);
        }

        const int o = b * NFREQ + p;
        out[o]              = mag;   // mag block [64,1,64,32]
        out[BB * NFREQ + o] = ph;    // phase block follows
    }
}

extern "C" void kernel_launch(void* const* d_in, const int* in_sizes, int n_in,
                              void* d_out, int out_size, void* d_ws, size_t ws_size,
                              hipStream_t stream) {
    const float* tris    = (const float*)d_in[0]; // [64,128,3,2] f32
    const int*   lengths = (const int*)d_in[1];   // [64] i32
    float*       out     = (float*)d_out;         // [2*64*2048] f32

    poly_cft_fused<<<dim3(PGRPS, BB), dim3(BLK), 0, stream>>>(tris, lengths, out);
}

// Round 6
// 73.356 us; speedup vs baseline: 1.5294x; 1.0346x over previous
//
#include <hip/hip_runtime.h>
#include <cmath>

// TERMINAL KERNEL (reverts R5's launder experiment to the best-measured R3
// body, 73.912 us).
//
// Session accounting (R0-R5):
//   dur_us 73.9 = 40.2 (harness 268MB poison-fill @83% HBM peak)
//               + ~14.6 (other harness dispatches/graph overhead)
//               + ~19.1 marginal (R4 3-launch measurement: ~10 launch ovh
//                 + ~9 us kernel).
//   Kernel issue floor: 130K wave-evals x ~116 issue-cyc (60 VALU + 56
//   quarter-rate trans) / 1024 SIMDs / 2.4GHz = 6.2 us balanced, ~9 us with
//   lengths-distribution imbalance -> kernel is AT its compute-issue roofline.
//   Four codegen-distinct variants landed within 73.9-76.3 us, confirming
//   insensitivity; phasor-table alternatives trade trig for equal-cost
//   LDS/L2 traffic (wash). No lever >= noise remains.
#define BB     64
#define MAXN   128
#define HH     64
#define WW     32
#define NFREQ  (HH*WW)      // 2048
#define BLK    256
#define NWAVE  4            // waves per block; each wave covers 64 points
#define PGRPS  (NFREQ/64)   // 32 point-groups of 64 points per batch elem

// pos_w[k] = float32(0.1 * (10^(1/30))^k) — bit-exactness validated previously.
__device__ __constant__ float c_posw[31] = {
    0.10000000000f, 0.10797751623f, 0.11659144012f, 0.12589254118f,
    0.13593563909f, 0.14677992676f, 0.15848931925f, 0.17113283042f,
    0.18478497970f, 0.19952623150f, 0.21544346900f, 0.23263050672f,
    0.25118864315f, 0.27122725793f, 0.29286445646f, 0.31622776602f,
    0.34145488738f, 0.36869450645f, 0.39810717055f, 0.42986623483f,
    0.46415888336f, 0.50118723363f, 0.54116952655f, 0.58434141336f,
    0.63095734448f, 0.68129206906f, 0.73564225446f, 0.79432823472f,
    0.85769589859f, 0.92611872813f, 1.00000000000f
};

// float32 constants exactly as the reference builds them:
#define PI_F      3.14159274101257324f   // np.float32(np.pi)
#define TWOPI_F   6.28318548202514648f   // 2*pi_f
#define FOURPI2_F ((4.0f * PI_F) * PI_F) // np.float32(4)*pi*pi

// sin(2*pi*x), cos(2*pi*x) via hardware v_sin_f32/v_cos_f32 (input in
// REVOLUTIONS, reduced to [0,1) with v_fract_f32 first).
__device__ __forceinline__ void sincos_2pi(float x, float* s, float* c) {
    float r = __builtin_amdgcn_fractf(x);
    *s = __builtin_amdgcn_sinf(r);
    *c = __builtin_amdgcn_cosf(r);
}

// Hot-loop mask quantities only (exact mul/mul/add, no FMA contraction).
struct Mask {
    float U_, V_, S;
    bool  sp;       // special AND not the DC lane (DC handled analytically)
};

__device__ __forceinline__ Mask pre_mask(float U, float V, float4 A4, float4 B4, bool dc) {
    Mask e;
    e.U_ = __fadd_rn(__fmul_rn(U, A4.z), __fmul_rn(V, A4.w));
    e.V_ = __fadd_rn(__fmul_rn(U, B4.x), __fmul_rn(V, B4.y));
    e.S  = __fadd_rn(e.U_, e.V_);
    e.sp = ((e.U_ == 0.0f) || (e.V_ == 0.0f) || (e.S == 0.0f)) && !dc;
    return e;
}

// FAST path: pure normal-case algebra; k = (2*area/4pi^2) * rcp(U_ V_ S).
__device__ __forceinline__ void eval_fast(const Mask& e, float U, float V,
                                          float4 A4, float4 B4,
                                          float& accR, float& accI) {
    const float tq = U * A4.x + V * A4.y;
    const float tr = tq + e.U_;
    const float ts = tr + e.V_;
    float sq, cq, sr, cr, ss, cs;
    sincos_2pi(tq, &sq, &cq);
    sincos_2pi(tr, &sr, &cr);
    sincos_2pi(ts, &ss, &cs);
    const float p1 = __builtin_amdgcn_rcpf((e.U_ * e.V_) * e.S);
    const float k  = B4.w * p1;
    const float re = e.S * cr - e.U_ * cs - e.V_ * cq;
    const float im = e.U_ * ss - e.S * sr + e.V_ * sq;
    accR = fmaf(k, re, accR);
    accI = fmaf(k, im, accI);
}

// COLD path: full branchless 4-way coefficient code, recomputed from LDS.
__device__ __forceinline__ void eval_slow_n(float U, float V, float4 A4, float4 B4,
                                            float& accR, float& accI) {
    const float U_ = __fadd_rn(__fmul_rn(U, A4.z), __fmul_rn(V, A4.w));
    const float V_ = __fadd_rn(__fmul_rn(U, B4.x), __fmul_rn(V, B4.y));
    const float S  = __fadd_rn(U_, V_);
    const bool uz = (U_ == 0.0f), vz = (V_ == 0.0f), sz = (S == 0.0f);

    const float tq = U * A4.x + V * A4.y;
    const float tr = tq + U_;
    const float ts = tr + V_;
    float sq, cq, sr, cr, ss, cs;
    sincos_2pi(tq, &sq, &cq);
    sincos_2pi(tr, &sr, &cr);
    sincos_2pi(ts, &ss, &cs);

    const float area = 0.5f * B4.z;
    const bool zero = uz && vz;
    const bool diag = sz && !zero;
    const bool u_m  = uz && !zero;
    const bool v_m  = vz && !zero;
    const bool nrm  = !(uz || vz || sz);

    const float twU = TWOPI_F * U_;
    const float twV = TWOPI_F * V_;

    const float Ac = nrm ? -U_ : (u_m ? 1.0f : 0.0f);
    const float Bc = nrm ?  S  : ((diag || v_m) ? 1.0f : 0.0f);
    const float Cc = nrm ? -V_ : -1.0f;
    const float Dc = v_m  ? twU : 0.0f;
    const float Ec = diag ? twU : (u_m ? twV : 0.0f);

    const float d1  = u_m ? V_ : U_;
    const float den = nrm ? (U_ * V_) * S : d1 * d1;
    const float p1  = __builtin_amdgcn_rcpf(FOURPI2_F * den);
    const float sgn = (diag || u_m) ? -2.0f : 2.0f;
    const float k   = zero ? 0.0f : sgn * area * p1;

    const float re =  Ac * cs + Bc * cr + Cc * cq + Dc * sr + Ec * sq;
    const float im = -(Ac * ss + Bc * sr + Cc * sq) + Dc * cr + Ec * cq;

    accR = fmaf(k, re, accR) + (zero ? area : 0.0f);
    accI = fmaf(k, im, accI);
}

__global__ __launch_bounds__(BLK) void poly_cft_fused(
    const float* __restrict__ tris,    // [64,128,3,2]
    const int*   __restrict__ lengths, // [64]
    float*       __restrict__ out)     // [2*64*2048]
{
    __shared__ float4 sA[MAXN];           // xq, yq, e1x, e1y          (2 KB)
    __shared__ float4 sB[MAXN];           // e2x, e2y, 2a, 2a/4pi^2    (2 KB)
    __shared__ float2 s_red[NWAVE][64];   // reduction scratch         (2 KB)

    const int pg   = blockIdx.x;           // 0..31 point group
    const int b    = blockIdx.y;           // 0..63 batch elem
    const int lane = threadIdx.x & 63;
    const int wv   = threadIdx.x >> 6;     // 0..3 wave id
    const int p    = (pg << 6) | lane;     // 0..2047 freq point
    const int h    = p >> 5;
    const int w    = p & 31;
    const bool dc  = (p == 992);           // h==31 && w==0 : U=V=0 lane

    const int N = lengths[b];

    // Stage all 128 triangles of this b once per block.
    if (threadIdx.x < MAXN) {
        const float2* tp = (const float2*)(tris + ((size_t)b * MAXN + threadIdx.x) * 6);
        const float2 v0 = tp[0], v1 = tp[1], v2 = tp[2];
        const float xq = v0.x, yq = v0.y, xr = v1.x, yr = v1.y, xs = v2.x, ys = v2.y;
        const float det  = xq * (yr - ys) + xr * (ys - yq) + xs * (yq - yr);
        const float area = fabsf(0.5f * det);
        const float a2   = 2.0f * area;
        sA[threadIdx.x] = make_float4(xq, yq, xr - xq, yr - yq);
        sB[threadIdx.x] = make_float4(xs - xr, ys - yr, a2, a2 * (1.0f / FOURPI2_F));
    }
    __syncthreads();

    // U = Wx[h], V = Wy[w] from the validated constant table.
    float U;
    if (h < 31)       U = -c_posw[30 - h];
    else if (h == 31) U = 0.0f;
    else if (h < 63)  U = c_posw[h - 32];
    else              U = 0.0f;   // padded row (masked before output)
    const float V = (w == 0) ? 0.0f : c_posw[w - 1];

    float accR = 0.0f, accI = 0.0f;

    // Quad loop: wave wv evaluates (n, n+4, n+8, n+12); per-wave accumulation
    // order (wv, wv+4, wv+8, ...) is preserved exactly in both branches.
    int n = wv;
    for (; n + 3 * NWAVE < N; n += 4 * NWAVE) {
        const float4 a0 = sA[n],             b0 = sB[n];
        const float4 a1 = sA[n +     NWAVE], b1 = sB[n +     NWAVE];
        const float4 a2 = sA[n + 2 * NWAVE], b2 = sB[n + 2 * NWAVE];
        const float4 a3 = sA[n + 3 * NWAVE], b3 = sB[n + 3 * NWAVE];
        const Mask ea = pre_mask(U, V, a0, b0, dc);
        const Mask eb = pre_mask(U, V, a1, b1, dc);
        const Mask ec = pre_mask(U, V, a2, b2, dc);
        const Mask ed = pre_mask(U, V, a3, b3, dc);

        if (__builtin_expect((long)__ballot(ea.sp || eb.sp || ec.sp || ed.sp), 0)) {
            eval_slow_n(U, V, a0, b0, accR, accI);
            eval_slow_n(U, V, a1, b1, accR, accI);
            eval_slow_n(U, V, a2, b2, accR, accI);
            eval_slow_n(U, V, a3, b3, accR, accI);
        } else {
            eval_fast(ea, U, V, a0, b0, accR, accI);
            eval_fast(eb, U, V, a1, b1, accR, accI);
            eval_fast(ec, U, V, a2, b2, accR, accI);
            eval_fast(ed, U, V, a3, b3, accR, accI);
        }
    }

    // Pair remainder.
    for (; n + NWAVE < N; n += 2 * NWAVE) {
        const float4 a0 = sA[n],         b0 = sB[n];
        const float4 a1 = sA[n + NWAVE], b1 = sB[n + NWAVE];
        const Mask ea = pre_mask(U, V, a0, b0, dc);
        const Mask eb = pre_mask(U, V, a1, b1, dc);
        if (__builtin_expect((long)__ballot(ea.sp || eb.sp), 0)) {
            eval_slow_n(U, V, a0, b0, accR, accI);
            eval_slow_n(U, V, a1, b1, accR, accI);
        } else {
            eval_fast(ea, U, V, a0, b0, accR, accI);
            eval_fast(eb, U, V, a1, b1, accR, accI);
        }
    }

    // Single remainder (at most one triangle per wave).
    for (; n < N; n += NWAVE) {
        const float4 a0 = sA[n], b0 = sB[n];
        const Mask ea = pre_mask(U, V, a0, b0, dc);
        if (__builtin_expect((long)__ballot(ea.sp), 0)) {
            eval_slow_n(U, V, a0, b0, accR, accI);
        } else {
            eval_fast(ea, U, V, a0, b0, accR, accI);
        }
    }

    s_red[wv][lane] = make_float2(accR, accI);
    __syncthreads();

    if (wv == 0) {
        float R = 0.0f, I = 0.0f;
#pragma unroll
        for (int k = 0; k < NWAVE; ++k) {
            const float2 v = s_red[k][lane];
            R += v.x;
            I += v.y;
        }
        // numpy's masked segment-sum adds exact +0.0 for invalid slots,
        // flipping -0.0 -> +0.0; reproduce (affects only zero signs).
        R += 0.0f;
        I += 0.0f;

        // DC lane (p==992): FT = sum of areas (exact analytic value).
        if (pg == 15) {
            float a0 = (lane < N)      ? 0.5f * sB[lane].z      : 0.0f;
            float a1 = (lane + 64 < N) ? 0.5f * sB[lane + 64].z : 0.0f;
            float s = a0 + a1;
#pragma unroll
            for (int o = 32; o > 0; o >>= 1) s += __shfl_down(s, o, 64);
            s = __shfl(s, 0, 64);
            if (lane == 32) { R = s; I = 0.0f; }
        }

        if (h == 63) { R = 0.0f; I = 0.0f; }   // pad row

        const float m2 = __fadd_rn(__fmul_rn(R, R), __fmul_rn(I, I));
        float mag, ph;
        if (m2 == 0.0f) {
            mag = 0.0f;
            ph  = atan2f(I, 1.0f);   // angle(0) = 0 semantics
        } else {
            mag = log1pf(sqrtf(m2));
            ph  = atan2f(I, R);
        }

        const int o = b * NFREQ + p;
        out[o]              = mag;   // mag block [64,1,64,32]
        out[BB * NFREQ + o] = ph;    // phase block follows
    }
}

extern "C" void kernel_launch(void* const* d_in, const int* in_sizes, int n_in,
                              void* d_out, int out_size, void* d_ws, size_t ws_size,
                              hipStream_t stream) {
    const float* tris    = (const float*)d_in[0]; // [64,128,3,2] f32
    const int*   lengths = (const int*)d_in[1];   // [64] i32
    float*       out     = (float*)d_out;         // [2*64*2048] f32

    poly_cft_fused<<<dim3(PGRPS, BB), dim3(BLK), 0, stream>>>(tris, lengths, out);
}